// Round 8
// baseline (54.371 us; speedup 1.0000x reference)
//
#include <hip/hip_runtime.h>
#include <hip/hip_fp16.h>

#define NCAM 5
#define NC 15
#define NCP 16              // padded channels; fp16 -> 32 B per pixel
#define FH 128
#define FW 240
#define HW (FH*FW)
#define CUBE 64
#define NVOX (CUBE*CUBE*CUBE)
#define TTHREADS 256
#define CSTR 24             // floats per (b,cam) struct
#define CAPPX 256           // staged-window capacity in pixels (4 per lane)
#define WBYTES 9216         // LDS bytes per wave (256 px * 36 B avg, padded)

// padded LDS offset for pixel slot s: 32 B payload + 16 B pad every 4 px
__device__ __forceinline__ int loff(int s) { return (s << 5) + ((s >> 2) << 4); }

// ---- transpose + (block 0) setup ----------------------------------------
__global__ __launch_bounds__(TTHREADS) void transpose_fm(
    const float* __restrict__ fm, __half* __restrict__ fmH,
    const float* __restrict__ gc, const float* __restrict__ space_c,
    const float* __restrict__ space_s, const float* __restrict__ sub_s,
    const float* __restrict__ centers, const float* __restrict__ trans,
    const float* __restrict__ cam_R, const float* __restrict__ cam_T,
    const float* __restrict__ cam_f, const float* __restrict__ cam_c,
    float* __restrict__ camS, int* __restrict__ bwin,
    float* __restrict__ out, int B)
{
    const int t = threadIdx.x;
    if (blockIdx.x == 0 && blockIdx.y == 0) {
        if (t < B) {                     // per-b window + offset (exact ref math)
            const int b = t;
            #pragma unroll
            for (int d = 0; d < 3; ++d) {
                float ssz = space_s[d], sc = space_c[d], sub = sub_s[d];
                int   fn  = (int)(ssz / sub * (CUBE - 1.0f)) + 1;
                float fnf = (float)fn;
                float scale = (fnf - 1.0f) / ssz;
                float bias  = -sub / 2.0f / ssz * (fnf - 1.0f) - scale * (sc - ssz / 2.0f);
                int ctl = (int)rintf(gc[b*7 + d] * scale + bias);
                int mask = 0;
                if (d < 2) {
                    mask = (int)((1.0f - gc[b*7 + 5 + d]) / 2.0f * (CUBE - 1.0f));
                    if (mask < 0) mask = 0;
                }
                int st = max(ctl + mask, 0);
                int en = min(ctl + CUBE - mask, fn);
                en = max(en, st + 1);
                bwin[b*12 + d]     = ctl;
                bwin[b*12 + 3 + d] = st;
                bwin[b*12 + 6 + d] = en;
                out[(size_t)B * NC * NVOX + b*3 + d] =
                    (float)ctl / (fnf - 1.0f) * ssz - ssz / 2.0f + sub / 2.0f;
            }
            bwin[b*12 + 9] = (gc[b*7 + 3] >= 0.0f) ? 1 : 0;
        }
        if (t < B * NCAM) {              // per-(b,cam) composed projection
            const int bk = t;
            float sA[3], bA[3];
            #pragma unroll
            for (int d = 0; d < 3; ++d) {
                float ssz = space_s[d], sub = sub_s[d];
                int   fn  = (int)(ssz / sub * (CUBE - 1.0f)) + 1;
                sA[d] = ssz / ((float)fn - 1.0f);
                bA[d] = space_c[d] - ssz * 0.5f;
            }
            const float* R = cam_R + bk*9;
            const float* T = cam_T + bk*3;
            float* P = camS + (size_t)bk * CSTR;
            #pragma unroll
            for (int i = 0; i < 3; ++i) {
                #pragma unroll
                for (int d = 0; d < 3; ++d) P[i*3 + d] = R[i*3 + d] * sA[d];
                P[9 + i] = R[i*3+0]*(bA[0]-T[0]) + R[i*3+1]*(bA[1]-T[1]) + R[i*3+2]*(bA[2]-T[2]);
            }
            P[12] = cam_f[bk*2+0];  P[13] = cam_f[bk*2+1];
            P[14] = cam_c[bk*2+0];  P[15] = cam_c[bk*2+1];
            P[16] = fmaxf(centers[bk*2+0]*2.0f, centers[bk*2+1]*2.0f);
            const float* tr = trans + bk*6;
            const float KX = 60.0f/239.0f, KY = 32.0f/127.0f;
            P[17] = tr[0]*KX;  P[18] = tr[1]*KX;  P[19] = tr[2]*KX - 120.0f;
            P[20] = tr[3]*KY;  P[21] = tr[4]*KY;  P[22] = tr[5]*KY - 64.0f;
            P[23] = 0.0f;
        }
    }
    const int p  = blockIdx.x * TTHREADS + t;
    const int cb = blockIdx.y;
    const float* src = fm + (size_t)cb * NC * HW + p;
    __half v[NCP];
    #pragma unroll
    for (int c = 0; c < NC; ++c) v[c] = __float2half(src[(size_t)c * HW]);
    v[15] = __float2half(0.0f);
    uint4* dst = (uint4*)(fmH + ((size_t)cb * HW + p) * NCP);
    dst[0] = *(const uint4*)(v);
    dst[1] = *(const uint4*)(v + 8);
}

// fused f16->f32 multiply-add: acc += wt * half(lo/hi of wrd)
#define FMA_MIX2(lo, hi, wt, wrd)                                             \
    asm("v_fma_mix_f32 %0, %1, %2, %0 op_sel_hi:[0,1,0]"                      \
        : "+v"(lo) : "v"(wt), "v"(wrd));                                      \
    asm("v_fma_mix_f32 %0, %1, %2, %0 op_sel:[0,1,0] op_sel_hi:[0,1,0]"       \
        : "+v"(hi) : "v"(wt), "v"(wrd));

// 15 channels: skip the pad channel's FMA (acc[15] never stored)
#define TAPFMA(wt, A, Bv)                                                     \
    FMA_MIX2(acc[0],  acc[1],  wt, A.x)                                       \
    FMA_MIX2(acc[2],  acc[3],  wt, A.y)                                       \
    FMA_MIX2(acc[4],  acc[5],  wt, A.z)                                       \
    FMA_MIX2(acc[6],  acc[7],  wt, A.w)                                       \
    FMA_MIX2(acc[8],  acc[9],  wt, Bv.x)                                      \
    FMA_MIX2(acc[10], acc[11], wt, Bv.y)                                      \
    FMA_MIX2(acc[12], acc[13], wt, Bv.z)                                      \
    asm("v_fma_mix_f32 %0, %1, %2, %0 op_sel_hi:[0,1,0]"                      \
        : "+v"(acc[14]) : "v"(wt), "v"(Bv.w));

// ---- main: lane = vk, per-wave LDS window staging ------------------------
__global__ __launch_bounds__(TTHREADS) void proj_main(
    const __half* __restrict__ fmH,      // [NCAM][B][HW][16] f16
    const float* __restrict__ camS,      // [B*NCAM][CSTR]
    const int* __restrict__ bwin,        // [B][12]
    float* __restrict__ out, int B)
{
    __shared__ char ldsA[4 * WBYTES];
    const int t = threadIdx.x, w = t >> 6, l = t & 63;
    const int bid = blockIdx.x;
    const int b = bid >> 10, bd = bid & 1023;
    const int n = bd * 256 + t;
    const int vi = bd >> 4, vj = (bd * 4 + w) & 63, vk = l;

    const int* Wn = bwin + b*12;
    const int fx = Wn[0] + vi, fy = Wn[1] + vj, fz = Wn[2] + vk;
    const bool valid = (fx >= Wn[3]) & (fx < Wn[6])
                     & (fy >= Wn[4]) & (fy < Wn[7])
                     & (fz >= Wn[5]) & (fz < Wn[8])
                     & (Wn[9] != 0);
    const float validf = valid ? 1.0f : 0.0f;

    float acc[15];
    #pragma unroll
    for (int c = 0; c < 15; ++c) acc[c] = 0.0f;

    if (__any(valid)) {
        const float fxf = (float)fx, fyf = (float)fy, fzf = (float)fz;
        const float* cs = camS + (size_t)(b * NCAM) * CSTR;
        char* myl = ldsA + w * WBYTES;

        for (int cam = 0; cam < NCAM; ++cam) {
            const float* P = cs + cam * CSTR;
            // ---- projection (composed constants) ----
            float X0 = fmaf(P[0], fxf, fmaf(P[1], fyf, fmaf(P[2], fzf, P[9])));
            float X1 = fmaf(P[3], fxf, fmaf(P[4], fyf, fmaf(P[5], fzf, P[10])));
            float X2 = fmaf(P[6], fxf, fmaf(P[7], fyf, fmaf(P[8], fzf, P[11])));
            float rz = __builtin_amdgcn_rcpf(X2);
            float px = fmaf(P[12]*X0, rz, P[14]);
            float py = fmaf(P[13]*X1, rz, P[15]);
            float mw = P[16];
            px = fminf(fmaxf(px, -1.0f), mw);
            py = fminf(fmaxf(py, -1.0f), mw);
            float ixf = fminf(fmaxf(fmaf(P[17], px, fmaf(P[18], py, P[19])), -132.0f), 132.0f) + 119.5f;
            float iyf = fminf(fmaxf(fmaf(P[20], px, fmaf(P[21], py, P[22])), -70.4f), 70.4f) + 63.5f;
            float x0f = floorf(ixf), y0f = floorf(iyf);
            float wx1 = ixf - x0f,  wy1 = iyf - y0f;
            float wx0 = 1.0f - wx1, wy0 = 1.0f - wy1;
            int x0 = (int)x0f, y0 = (int)y0f, x1 = x0 + 1, y1 = y0 + 1;
            bool vx0 = (unsigned)x0 <= (FW-1), vx1 = (unsigned)x1 <= (FW-1);
            bool vy0 = (unsigned)y0 <= (FH-1), vy1 = (unsigned)y1 <= (FH-1);
            float w0 = ((vx0 && vy0) ? wx0*wy0 : 0.0f) * validf;
            float w1 = ((vx1 && vy0) ? wx1*wy0 : 0.0f) * validf;
            float w2 = ((vx0 && vy1) ? wx0*wy1 : 0.0f) * validf;
            float w3 = ((vx1 && vy1) ? wx1*wy1 : 0.0f) * validf;
            int xc0 = min(max(x0,0),FW-1), xc1 = min(max(x1,0),FW-1);
            int yc0 = min(max(y0,0),FH-1), yc1 = min(max(y1,0),FH-1);

            // ---- wave bbox reduce (butterfly over 64 lanes) ----
            int bx0 = xc0, bx1 = xc1, by0 = yc0, by1 = yc1;
            #pragma unroll
            for (int m = 1; m < 64; m <<= 1) {
                bx0 = min(bx0, __shfl_xor(bx0, m));
                bx1 = max(bx1, __shfl_xor(bx1, m));
                by0 = min(by0, __shfl_xor(by0, m));
                by1 = max(by1, __shfl_xor(by1, m));
            }
            int Wd = bx1 - bx0 + 1, Hd = by1 - by0 + 1;
            int lw = (Wd > 1) ? (32 - __clz(Wd - 1)) : 0;
            int A  = Hd << lw;

            const __half* bp = fmH + (size_t)(cam*B + b) * HW * NCP;
            uint4 a0, b0, a1, b1, a2, b2, a3, b3;

            if (A <= CAPPX) {
                // stage window: lane covers slots l, l+64, l+128, l+192
                #pragma unroll
                for (int k = 0; k < 4; ++k) {
                    int s = l + (k << 6);
                    if (s < A) {
                        int spy = by0 + (s >> lw);
                        int spx = min(bx0 + (s & ((1 << lw) - 1)), FW-1);
                        const uint4* q = (const uint4*)(bp + (size_t)(spy*FW + spx) * NCP);
                        uint4 v0 = q[0], v1 = q[1];
                        char* dp = myl + loff(s);
                        *(uint4*)dp        = v0;
                        *(uint4*)(dp + 16) = v1;
                    }
                }
                __asm__ __volatile__("s_waitcnt lgkmcnt(0)" ::: "memory");
                int dx  = xc1 - xc0;
                int s00 = ((yc0 - by0) << lw) + (xc0 - bx0);
                int s01 = ((yc1 - by0) << lw) + (xc0 - bx0);
                const char* r;
                r = myl + loff(s00);      a0 = *(const uint4*)r; b0 = *(const uint4*)(r+16);
                r = myl + loff(s00+dx);   a1 = *(const uint4*)r; b1 = *(const uint4*)(r+16);
                r = myl + loff(s01);      a2 = *(const uint4*)r; b2 = *(const uint4*)(r+16);
                r = myl + loff(s01+dx);   a3 = *(const uint4*)r; b3 = *(const uint4*)(r+16);
            } else {
                // fallback: direct global taps (old path)
                const uint4* q0 = (const uint4*)(bp + (size_t)(yc0*FW + xc0) * NCP);
                const uint4* q1 = (const uint4*)(bp + (size_t)(yc0*FW + xc1) * NCP);
                const uint4* q2 = (const uint4*)(bp + (size_t)(yc1*FW + xc0) * NCP);
                const uint4* q3 = (const uint4*)(bp + (size_t)(yc1*FW + xc1) * NCP);
                a0 = q0[0]; b0 = q0[1];
                a1 = q1[0]; b1 = q1[1];
                a2 = q2[0]; b2 = q2[1];
                a3 = q3[0]; b3 = q3[1];
            }

            TAPFMA(w0, a0, b0)
            TAPFMA(w1, a1, b1)
            TAPFMA(w2, a2, b2)
            TAPFMA(w3, a3, b3)
        }
    }

    const float RINV = 0.19999996000000800f;  // 1/(5+1e-6)
    #pragma unroll
    for (int c = 0; c < NC; ++c) {
        float v = fminf(fmaxf(acc[c] * RINV, 0.0f), 1.0f);
        out[((size_t)(b*NC + c)) * NVOX + n] = v;
    }
}

// ---- fallback (round-1 style, f32 direct) if ws is too small ----
__global__ __launch_bounds__(256) void proj_fallback(
    const float* __restrict__ fm, const float* __restrict__ gc,
    const float* __restrict__ space_center, const float* __restrict__ space_size,
    const float* __restrict__ sub_size, const float* __restrict__ centers,
    const float* __restrict__ trans, const float* __restrict__ cam_R,
    const float* __restrict__ cam_T, const float* __restrict__ cam_f,
    const float* __restrict__ cam_c, float* __restrict__ out, int B)
{
    const int b = blockIdx.x / (NVOX/256);
    const int n = (blockIdx.x % (NVOX/256)) * 256 + threadIdx.x;
    float ctlf[3], fnf[3], sc[3], ssz[3];
    int   ctl[3], st[3], en[3];
    #pragma unroll
    for (int d = 0; d < 3; ++d) {
        ssz[d] = space_size[d];
        sc[d]  = space_center[d];
        float sub = sub_size[d];
        int fn = (int)(ssz[d] / sub * (CUBE - 1.0f)) + 1;
        fnf[d] = (float)fn;
        float scale = (fnf[d] - 1.0f) / ssz[d];
        float bias  = -sub / 2.0f / ssz[d] * (fnf[d] - 1.0f)
                      - scale * (sc[d] - ssz[d] / 2.0f);
        int c_tl = (int)rintf(gc[b*7 + d] * scale + bias);
        ctl[d]  = c_tl;  ctlf[d] = (float)c_tl;
        int mask = 0;
        if (d < 2) {
            mask = (int)((1.0f - gc[b*7 + 5 + d]) / 2.0f * (CUBE - 1.0f));
            if (mask < 0) mask = 0;
        }
        st[d] = max(c_tl + mask, 0);
        int e = min(c_tl + CUBE - mask, fn);
        en[d] = max(e, st[d] + 1);
    }
    if (n < 3) {
        int d = n;
        out[(size_t)B * NC * NVOX + b*3 + d] =
            ctlf[d] / (fnf[d] - 1.0f) * ssz[d] - ssz[d] / 2.0f + sub_size[d] / 2.0f;
    }
    const int vi = n >> 12, vj = (n >> 6) & 63, vk = n & 63;
    const int fx = ctl[0] + vi, fy = ctl[1] + vj, fz = ctl[2] + vk;
    const bool valid = (fx >= st[0]) & (fx < en[0]) & (fy >= st[1]) & (fy < en[1])
                     & (fz >= st[2]) & (fz < en[2]) & (gc[b*7 + 3] >= 0.0f);
    float acc[NC];
    #pragma unroll
    for (int c = 0; c < NC; ++c) acc[c] = 0.0f;
    if (valid) {
        const float wxw = sc[0] - ssz[0]*0.5f + (float)fx / (fnf[0]-1.0f) * ssz[0];
        const float wyw = sc[1] - ssz[1]*0.5f + (float)fy / (fnf[1]-1.0f) * ssz[1];
        const float wzw = sc[2] - ssz[2]*0.5f + (float)fz / (fnf[2]-1.0f) * ssz[2];
        for (int cam = 0; cam < NCAM; ++cam) {
            const int bk = b*NCAM + cam;
            const float* R = cam_R + bk*9;
            const float* T = cam_T + bk*3;
            float r0 = wxw - T[0], r1 = wyw - T[1], r2 = wzw - T[2];
            float X0 = R[0]*r0 + R[1]*r1 + R[2]*r2;
            float X1 = R[3]*r0 + R[4]*r1 + R[5]*r2;
            float X2 = R[6]*r0 + R[7]*r1 + R[8]*r2;
            float px = cam_f[bk*2+0]*X0/X2 + cam_c[bk*2+0];
            float py = cam_f[bk*2+1]*X1/X2 + cam_c[bk*2+1];
            float maxwh = fmaxf(centers[bk*2+0]*2.0f, centers[bk*2+1]*2.0f);
            px = fminf(fmaxf(px, -1.0f), maxwh);
            py = fminf(fmaxf(py, -1.0f), maxwh);
            const float* tr = trans + bk*6;
            float tx = (tr[0]*px + tr[1]*py + tr[2]) * 0.25f;
            float ty = (tr[3]*px + tr[4]*py + tr[5]) * 0.25f;
            float gx = fminf(fmaxf(tx/239.0f*2.0f - 1.0f, -1.1f), 1.1f);
            float gy = fminf(fmaxf(ty/127.0f*2.0f - 1.0f, -1.1f), 1.1f);
            float ixf = (gx + 1.0f)*(FW*0.5f) - 0.5f;
            float iyf = (gy + 1.0f)*(FH*0.5f) - 0.5f;
            float x0f = floorf(ixf), y0f = floorf(iyf);
            float wx1 = ixf - x0f,  wy1 = iyf - y0f;
            float wx0 = 1.0f - wx1, wy0 = 1.0f - wy1;
            int x0 = (int)x0f, y0 = (int)y0f, x1 = x0 + 1, y1 = y0 + 1;
            bool vx0 = (x0 >= 0) & (x0 <= FW-1), vx1 = (x1 >= 0) & (x1 <= FW-1);
            bool vy0 = (y0 >= 0) & (y0 <= FH-1), vy1 = (y1 >= 0) & (y1 <= FH-1);
            float w00 = wx0*wy0*(float)(vx0 & vy0);
            float w10 = wx1*wy0*(float)(vx1 & vy0);
            float w01 = wx0*wy1*(float)(vx0 & vy1);
            float w11 = wx1*wy1*(float)(vx1 & vy1);
            int xc0 = min(max(x0,0),FW-1), xc1 = min(max(x1,0),FW-1);
            int yc0 = min(max(y0,0),FH-1), yc1 = min(max(y1,0),FH-1);
            int o00 = yc0*FW + xc0, o10 = yc0*FW + xc1;
            int o01 = yc1*FW + xc0, o11 = yc1*FW + xc1;
            const float* base = fm + ((size_t)(cam*B + b)) * NC * HW;
            #pragma unroll
            for (int c = 0; c < NC; ++c) {
                const float* p = base + c*HW;
                acc[c] += w00*p[o00] + w10*p[o10] + w01*p[o01] + w11*p[o11];
            }
        }
    }
    const float invd = (float)(5.0 + 1e-6);
    #pragma unroll
    for (int c = 0; c < NC; ++c) {
        float v = acc[c] / invd;
        v = fminf(fmaxf(v, 0.0f), 1.0f);
        out[((size_t)(b*NC + c)) * NVOX + n] = v;
    }
}

extern "C" void kernel_launch(void* const* d_in, const int* in_sizes, int n_in,
                              void* d_out, int out_size, void* d_ws, size_t ws_size,
                              hipStream_t stream) {
    const float* fm        = (const float*)d_in[0];
    const float* gc        = (const float*)d_in[1];
    const float* space_c   = (const float*)d_in[2];
    const float* space_s   = (const float*)d_in[3];
    const float* sub_s     = (const float*)d_in[4];
    const float* centers   = (const float*)d_in[6];
    const float* trans     = (const float*)d_in[7];
    const float* cam_R     = (const float*)d_in[8];
    const float* cam_T     = (const float*)d_in[9];
    const float* cam_f     = (const float*)d_in[10];
    const float* cam_c     = (const float*)d_in[11];
    float* out = (float*)d_out;
    const int B = in_sizes[1] / 7;

    const size_t FMHB   = (size_t)NCAM * B * HW * NCP * sizeof(__half);
    const size_t CAMOFF = (FMHB + 255) & ~(size_t)255;
    const size_t BWOFF  = (CAMOFF + (size_t)B * NCAM * CSTR * 4 + 255) & ~(size_t)255;
    const size_t NEED   = BWOFF + (size_t)B * 48;

    if (ws_size >= NEED) {
        __half* fmH  = (__half*)d_ws;
        float*  camS = (float*)((char*)d_ws + CAMOFF);
        int*    bwin = (int*)((char*)d_ws + BWOFF);
        dim3 tg(HW / TTHREADS, NCAM * B);
        hipLaunchKernelGGL(transpose_fm, tg, dim3(TTHREADS), 0, stream,
                           fm, fmH, gc, space_c, space_s, sub_s, centers, trans,
                           cam_R, cam_T, cam_f, cam_c, camS, bwin, out, B);
        dim3 grid(B * 1024), block(TTHREADS);
        hipLaunchKernelGGL(proj_main, grid, block, 0, stream,
                           fmH, camS, bwin, out, B);
    } else {
        dim3 grid(B * (NVOX/256)), block(256);
        hipLaunchKernelGGL(proj_fallback, grid, block, 0, stream,
                           fm, gc, space_c, space_s, sub_s,
                           centers, trans, cam_R, cam_T, cam_f, cam_c, out, B);
    }
}

// Round 9
// 40.071 us; speedup vs baseline: 1.3569x; 1.3569x over previous
//
#include <hip/hip_runtime.h>
#include <hip/hip_fp16.h>

#define NCAM 5
#define NC 15
#define NCP 16              // padded channels; fp16 -> 32 B per pixel
#define FH 128
#define FW 240
#define HW (FH*FW)
#define CUBE 64
#define NVOX (CUBE*CUBE*CUBE)
#define TTHREADS 256
#define MTHREADS 256
#define CSTR 24             // floats per (b,cam) struct

// ---- transpose + (block 0) setup ----------------------------------------
__global__ __launch_bounds__(TTHREADS) void transpose_fm(
    const float* __restrict__ fm, __half* __restrict__ fmH,
    const float* __restrict__ gc, const float* __restrict__ space_c,
    const float* __restrict__ space_s, const float* __restrict__ sub_s,
    const float* __restrict__ centers, const float* __restrict__ trans,
    const float* __restrict__ cam_R, const float* __restrict__ cam_T,
    const float* __restrict__ cam_f, const float* __restrict__ cam_c,
    float* __restrict__ camS, int* __restrict__ bwin,
    float* __restrict__ out, int B)
{
    const int t = threadIdx.x;
    if (blockIdx.x == 0 && blockIdx.y == 0) {
        if (t < B) {                     // per-b window + offset (exact ref math)
            const int b = t;
            #pragma unroll
            for (int d = 0; d < 3; ++d) {
                float ssz = space_s[d], sc = space_c[d], sub = sub_s[d];
                int   fn  = (int)(ssz / sub * (CUBE - 1.0f)) + 1;
                float fnf = (float)fn;
                float scale = (fnf - 1.0f) / ssz;
                float bias  = -sub / 2.0f / ssz * (fnf - 1.0f) - scale * (sc - ssz / 2.0f);
                int ctl = (int)rintf(gc[b*7 + d] * scale + bias);
                int mask = 0;
                if (d < 2) {
                    mask = (int)((1.0f - gc[b*7 + 5 + d]) / 2.0f * (CUBE - 1.0f));
                    if (mask < 0) mask = 0;
                }
                int st = max(ctl + mask, 0);
                int en = min(ctl + CUBE - mask, fn);
                en = max(en, st + 1);
                bwin[b*12 + d]     = ctl;
                bwin[b*12 + 3 + d] = st;
                bwin[b*12 + 6 + d] = en;
                out[(size_t)B * NC * NVOX + b*3 + d] =
                    (float)ctl / (fnf - 1.0f) * ssz - ssz / 2.0f + sub / 2.0f;
            }
            bwin[b*12 + 9] = (gc[b*7 + 3] >= 0.0f) ? 1 : 0;
        }
        if (t < B * NCAM) {              // per-(b,cam) composed projection
            const int bk = t;
            float sA[3], bA[3];
            #pragma unroll
            for (int d = 0; d < 3; ++d) {
                float ssz = space_s[d], sub = sub_s[d];
                int   fn  = (int)(ssz / sub * (CUBE - 1.0f)) + 1;
                sA[d] = ssz / ((float)fn - 1.0f);
                bA[d] = space_c[d] - ssz * 0.5f;
            }
            const float* R = cam_R + bk*9;
            const float* T = cam_T + bk*3;
            float* P = camS + (size_t)bk * CSTR;
            #pragma unroll
            for (int i = 0; i < 3; ++i) {
                #pragma unroll
                for (int d = 0; d < 3; ++d) P[i*3 + d] = R[i*3 + d] * sA[d];
                P[9 + i] = R[i*3+0]*(bA[0]-T[0]) + R[i*3+1]*(bA[1]-T[1]) + R[i*3+2]*(bA[2]-T[2]);
            }
            P[12] = cam_f[bk*2+0];  P[13] = cam_f[bk*2+1];
            P[14] = cam_c[bk*2+0];  P[15] = cam_c[bk*2+1];
            P[16] = fmaxf(centers[bk*2+0]*2.0f, centers[bk*2+1]*2.0f);
            const float* tr = trans + bk*6;
            const float KX = 60.0f/239.0f, KY = 32.0f/127.0f; // fold 0.25*(2/HM)*halfdim
            P[17] = tr[0]*KX;  P[18] = tr[1]*KX;  P[19] = tr[2]*KX - 120.0f;
            P[20] = tr[3]*KY;  P[21] = tr[4]*KY;  P[22] = tr[5]*KY - 64.0f;
            P[23] = 0.0f;
        }
    }
    const int p  = blockIdx.x * TTHREADS + t;
    const int cb = blockIdx.y;
    const float* src = fm + (size_t)cb * NC * HW + p;
    __half v[NCP];
    #pragma unroll
    for (int c = 0; c < NC; ++c) v[c] = __float2half(src[(size_t)c * HW]);
    v[15] = __float2half(0.0f);
    uint4* dst = (uint4*)(fmH + ((size_t)cb * HW + p) * NCP);
    dst[0] = *(const uint4*)(v);
    dst[1] = *(const uint4*)(v + 8);
}

// fused f16->f32 multiply-add: acc += wt * half(lo/hi of wrd)
#define FMA_MIX2(lo, hi, wt, wrd)                                             \
    asm("v_fma_mix_f32 %0, %1, %2, %0 op_sel_hi:[0,1,0]"                      \
        : "+v"(lo) : "v"(wt), "v"(wrd));                                      \
    asm("v_fma_mix_f32 %0, %1, %2, %0 op_sel:[0,1,0] op_sel_hi:[0,1,0]"       \
        : "+v"(hi) : "v"(wt), "v"(wrd));

// 15 channels: skip the dead pad-channel FMA
#define TAPFMA(wt, A, Bv)                                                     \
    FMA_MIX2(acc[0],  acc[1],  wt, A.x)                                       \
    FMA_MIX2(acc[2],  acc[3],  wt, A.y)                                       \
    FMA_MIX2(acc[4],  acc[5],  wt, A.z)                                       \
    FMA_MIX2(acc[6],  acc[7],  wt, A.w)                                       \
    FMA_MIX2(acc[8],  acc[9],  wt, Bv.x)                                      \
    FMA_MIX2(acc[10], acc[11], wt, Bv.y)                                      \
    FMA_MIX2(acc[12], acc[13], wt, Bv.z)                                      \
    asm("v_fma_mix_f32 %0, %1, %2, %0 op_sel_hi:[0,1,0]"                      \
        : "+v"(acc[14]) : "v"(wt), "v"(Bv.w));

// ---- main: R4 loop shape + composed constants + XCD-chunked swizzle ------
__global__ __launch_bounds__(MTHREADS) void proj_main(
    const __half* __restrict__ fmH,      // [NCAM][B][HW][16] f16
    const float* __restrict__ camS,      // [B*NCAM][CSTR]
    const int* __restrict__ bwin,        // [B][12]: ctl[3], st[3], en[3], flag
    float* __restrict__ out, int B)
{
    // bijective chunked XCD swizzle: each XCD gets a contiguous wgid range
    const unsigned nwg = gridDim.x;
    const unsigned q = nwg >> 3, r = nwg & 7;
    const unsigned xcd = blockIdx.x & 7, idx = blockIdx.x >> 3;
    const unsigned wgid = (xcd < r ? xcd * (q + 1) : r * (q + 1) + (xcd - r) * q) + idx;

    const int b = wgid >> 10;                    // 1024 blocks per b
    const int n = (int)(wgid & 1023) * MTHREADS + threadIdx.x;
    const int vi = n >> 12, vj = (n >> 6) & 63, vk = n & 63;

    const int* W = bwin + b*12;
    const int fx = W[0] + vi, fy = W[1] + vj, fz = W[2] + vk;
    const bool valid = (fx >= W[3]) & (fx < W[6])
                     & (fy >= W[4]) & (fy < W[7])
                     & (fz >= W[5]) & (fz < W[8])
                     & (W[9] != 0);

    float acc[15];
    #pragma unroll
    for (int c = 0; c < 15; ++c) acc[c] = 0.0f;

    if (valid) {
        const float fxf = (float)fx, fyf = (float)fy, fzf = (float)fz;
        const float* cs = camS + (size_t)(b * NCAM) * CSTR;

        #pragma unroll
        for (int cam = 0; cam < NCAM; ++cam) {
            const float* P = cs + cam * CSTR;
            float X0 = fmaf(P[0], fxf, fmaf(P[1], fyf, fmaf(P[2], fzf, P[9])));
            float X1 = fmaf(P[3], fxf, fmaf(P[4], fyf, fmaf(P[5], fzf, P[10])));
            float X2 = fmaf(P[6], fxf, fmaf(P[7], fyf, fmaf(P[8], fzf, P[11])));
            float rz = __builtin_amdgcn_rcpf(X2);
            float px = fmaf(P[12]*X0, rz, P[14]);
            float py = fmaf(P[13]*X1, rz, P[15]);
            float mw = P[16];
            px = fminf(fmaxf(px, -1.0f), mw);
            py = fminf(fmaxf(py, -1.0f), mw);
            float ixf = fminf(fmaxf(fmaf(P[17], px, fmaf(P[18], py, P[19])), -132.0f), 132.0f) + 119.5f;
            float iyf = fminf(fmaxf(fmaf(P[20], px, fmaf(P[21], py, P[22])), -70.4f), 70.4f) + 63.5f;
            float x0f = floorf(ixf), y0f = floorf(iyf);
            float wx1 = ixf - x0f,  wy1 = iyf - y0f;
            float wx0 = 1.0f - wx1, wy0 = 1.0f - wy1;
            int x0 = (int)x0f, y0 = (int)y0f, x1 = x0 + 1, y1 = y0 + 1;
            bool vx0 = (unsigned)x0 <= (FW-1), vx1 = (unsigned)x1 <= (FW-1);
            bool vy0 = (unsigned)y0 <= (FH-1), vy1 = (unsigned)y1 <= (FH-1);
            float w0 = (vx0 && vy0) ? wx0*wy0 : 0.0f;
            float w1 = (vx1 && vy0) ? wx1*wy0 : 0.0f;
            float w2 = (vx0 && vy1) ? wx0*wy1 : 0.0f;
            float w3 = (vx1 && vy1) ? wx1*wy1 : 0.0f;
            int xc0 = min(max(x0,0),FW-1), xc1 = min(max(x1,0),FW-1);
            int yc0 = min(max(y0,0),FH-1), yc1 = min(max(y1,0),FH-1);

            const __half* bp = fmH + (size_t)(cam*B + b) * HW * NCP;
            const uint4* q0 = (const uint4*)(bp + (size_t)(yc0*FW + xc0) * NCP);
            const uint4* q1 = (const uint4*)(bp + (size_t)(yc0*FW + xc1) * NCP);
            const uint4* q2 = (const uint4*)(bp + (size_t)(yc1*FW + xc0) * NCP);
            const uint4* q3 = (const uint4*)(bp + (size_t)(yc1*FW + xc1) * NCP);
            uint4 a0 = q0[0], b0 = q0[1];
            uint4 a1 = q1[0], b1 = q1[1];
            uint4 a2 = q2[0], b2 = q2[1];
            uint4 a3 = q3[0], b3 = q3[1];

            TAPFMA(w0, a0, b0)
            TAPFMA(w1, a1, b1)
            TAPFMA(w2, a2, b2)
            TAPFMA(w3, a3, b3)
        }
    }

    const float RINV = 0.19999996000000800f;  // 1/(5+1e-6)
    #pragma unroll
    for (int c = 0; c < NC; ++c) {
        float v = fminf(fmaxf(acc[c] * RINV, 0.0f), 1.0f);
        out[((size_t)(b*NC + c)) * NVOX + n] = v;
    }
}

// ---- fallback (round-1 style, f32 direct) if ws is too small ----
__global__ __launch_bounds__(256) void proj_fallback(
    const float* __restrict__ fm, const float* __restrict__ gc,
    const float* __restrict__ space_center, const float* __restrict__ space_size,
    const float* __restrict__ sub_size, const float* __restrict__ centers,
    const float* __restrict__ trans, const float* __restrict__ cam_R,
    const float* __restrict__ cam_T, const float* __restrict__ cam_f,
    const float* __restrict__ cam_c, float* __restrict__ out, int B)
{
    const int b = blockIdx.x / (NVOX/256);
    const int n = (blockIdx.x % (NVOX/256)) * 256 + threadIdx.x;
    float ctlf[3], fnf[3], sc[3], ssz[3];
    int   ctl[3], st[3], en[3];
    #pragma unroll
    for (int d = 0; d < 3; ++d) {
        ssz[d] = space_size[d];
        sc[d]  = space_center[d];
        float sub = sub_size[d];
        int fn = (int)(ssz[d] / sub * (CUBE - 1.0f)) + 1;
        fnf[d] = (float)fn;
        float scale = (fnf[d] - 1.0f) / ssz[d];
        float bias  = -sub / 2.0f / ssz[d] * (fnf[d] - 1.0f)
                      - scale * (sc[d] - ssz[d] / 2.0f);
        int c_tl = (int)rintf(gc[b*7 + d] * scale + bias);
        ctl[d]  = c_tl;  ctlf[d] = (float)c_tl;
        int mask = 0;
        if (d < 2) {
            mask = (int)((1.0f - gc[b*7 + 5 + d]) / 2.0f * (CUBE - 1.0f));
            if (mask < 0) mask = 0;
        }
        st[d] = max(c_tl + mask, 0);
        int e = min(c_tl + CUBE - mask, fn);
        en[d] = max(e, st[d] + 1);
    }
    if (n < 3) {
        int d = n;
        out[(size_t)B * NC * NVOX + b*3 + d] =
            ctlf[d] / (fnf[d] - 1.0f) * ssz[d] - ssz[d] / 2.0f + sub_size[d] / 2.0f;
    }
    const int vi = n >> 12, vj = (n >> 6) & 63, vk = n & 63;
    const int fx = ctl[0] + vi, fy = ctl[1] + vj, fz = ctl[2] + vk;
    const bool valid = (fx >= st[0]) & (fx < en[0]) & (fy >= st[1]) & (fy < en[1])
                     & (fz >= st[2]) & (fz < en[2]) & (gc[b*7 + 3] >= 0.0f);
    float acc[NC];
    #pragma unroll
    for (int c = 0; c < NC; ++c) acc[c] = 0.0f;
    if (valid) {
        const float wxw = sc[0] - ssz[0]*0.5f + (float)fx / (fnf[0]-1.0f) * ssz[0];
        const float wyw = sc[1] - ssz[1]*0.5f + (float)fy / (fnf[1]-1.0f) * ssz[1];
        const float wzw = sc[2] - ssz[2]*0.5f + (float)fz / (fnf[2]-1.0f) * ssz[2];
        for (int cam = 0; cam < NCAM; ++cam) {
            const int bk = b*NCAM + cam;
            const float* R = cam_R + bk*9;
            const float* T = cam_T + bk*3;
            float r0 = wxw - T[0], r1 = wyw - T[1], r2 = wzw - T[2];
            float X0 = R[0]*r0 + R[1]*r1 + R[2]*r2;
            float X1 = R[3]*r0 + R[4]*r1 + R[5]*r2;
            float X2 = R[6]*r0 + R[7]*r1 + R[8]*r2;
            float px = cam_f[bk*2+0]*X0/X2 + cam_c[bk*2+0];
            float py = cam_f[bk*2+1]*X1/X2 + cam_c[bk*2+1];
            float maxwh = fmaxf(centers[bk*2+0]*2.0f, centers[bk*2+1]*2.0f);
            px = fminf(fmaxf(px, -1.0f), maxwh);
            py = fminf(fmaxf(py, -1.0f), maxwh);
            const float* tr = trans + bk*6;
            float tx = (tr[0]*px + tr[1]*py + tr[2]) * 0.25f;
            float ty = (tr[3]*px + tr[4]*py + tr[5]) * 0.25f;
            float gx = fminf(fmaxf(tx/239.0f*2.0f - 1.0f, -1.1f), 1.1f);
            float gy = fminf(fmaxf(ty/127.0f*2.0f - 1.0f, -1.1f), 1.1f);
            float ixf = (gx + 1.0f)*(FW*0.5f) - 0.5f;
            float iyf = (gy + 1.0f)*(FH*0.5f) - 0.5f;
            float x0f = floorf(ixf), y0f = floorf(iyf);
            float wx1 = ixf - x0f,  wy1 = iyf - y0f;
            float wx0 = 1.0f - wx1, wy0 = 1.0f - wy1;
            int x0 = (int)x0f, y0 = (int)y0f, x1 = x0 + 1, y1 = y0 + 1;
            bool vx0 = (x0 >= 0) & (x0 <= FW-1), vx1 = (x1 >= 0) & (x1 <= FW-1);
            bool vy0 = (y0 >= 0) & (y0 <= FH-1), vy1 = (y1 >= 0) & (y1 <= FH-1);
            float w00 = wx0*wy0*(float)(vx0 & vy0);
            float w10 = wx1*wy0*(float)(vx1 & vy0);
            float w01 = wx0*wy1*(float)(vx0 & vy1);
            float w11 = wx1*wy1*(float)(vx1 & vy1);
            int xc0 = min(max(x0,0),FW-1), xc1 = min(max(x1,0),FW-1);
            int yc0 = min(max(y0,0),FH-1), yc1 = min(max(y1,0),FH-1);
            int o00 = yc0*FW + xc0, o10 = yc0*FW + xc1;
            int o01 = yc1*FW + xc0, o11 = yc1*FW + xc1;
            const float* base = fm + ((size_t)(cam*B + b)) * NC * HW;
            #pragma unroll
            for (int c = 0; c < NC; ++c) {
                const float* p = base + c*HW;
                acc[c] += w00*p[o00] + w10*p[o10] + w01*p[o01] + w11*p[o11];
            }
        }
    }
    const float invd = (float)(5.0 + 1e-6);
    #pragma unroll
    for (int c = 0; c < NC; ++c) {
        float v = acc[c] / invd;
        v = fminf(fmaxf(v, 0.0f), 1.0f);
        out[((size_t)(b*NC + c)) * NVOX + n] = v;
    }
}

extern "C" void kernel_launch(void* const* d_in, const int* in_sizes, int n_in,
                              void* d_out, int out_size, void* d_ws, size_t ws_size,
                              hipStream_t stream) {
    const float* fm        = (const float*)d_in[0];
    const float* gc        = (const float*)d_in[1];
    const float* space_c   = (const float*)d_in[2];
    const float* space_s   = (const float*)d_in[3];
    const float* sub_s     = (const float*)d_in[4];
    const float* centers   = (const float*)d_in[6];
    const float* trans     = (const float*)d_in[7];
    const float* cam_R     = (const float*)d_in[8];
    const float* cam_T     = (const float*)d_in[9];
    const float* cam_f     = (const float*)d_in[10];
    const float* cam_c     = (const float*)d_in[11];
    float* out = (float*)d_out;
    const int B = in_sizes[1] / 7;

    const size_t FMHB   = (size_t)NCAM * B * HW * NCP * sizeof(__half);
    const size_t CAMOFF = (FMHB + 255) & ~(size_t)255;
    const size_t BWOFF  = (CAMOFF + (size_t)B * NCAM * CSTR * 4 + 255) & ~(size_t)255;
    const size_t NEED   = BWOFF + (size_t)B * 48;

    if (ws_size >= NEED) {
        __half* fmH  = (__half*)d_ws;
        float*  camS = (float*)((char*)d_ws + CAMOFF);
        int*    bwin = (int*)((char*)d_ws + BWOFF);
        dim3 tg(HW / TTHREADS, NCAM * B);
        hipLaunchKernelGGL(transpose_fm, tg, dim3(TTHREADS), 0, stream,
                           fm, fmH, gc, space_c, space_s, sub_s, centers, trans,
                           cam_R, cam_T, cam_f, cam_c, camS, bwin, out, B);
        dim3 grid(B * 1024), block(MTHREADS);
        hipLaunchKernelGGL(proj_main, grid, block, 0, stream,
                           fmH, camS, bwin, out, B);
    } else {
        dim3 grid(B * (NVOX/256)), block(256);
        hipLaunchKernelGGL(proj_fallback, grid, block, 0, stream,
                           fm, gc, space_c, space_s, sub_s,
                           centers, trans, cam_R, cam_T, cam_f, cam_c, out, B);
    }
}

// Round 10
// 39.869 us; speedup vs baseline: 1.3637x; 1.0050x over previous
//
#include <hip/hip_runtime.h>
#include <hip/hip_fp16.h>

#define NCAM 5
#define NC 15
#define NCP 16              // padded channels; fp16 -> 32 B per pixel
#define FH 128
#define FW 240
#define HW (FH*FW)
#define CUBE 64
#define NVOX (CUBE*CUBE*CUBE)
#define TTHREADS 256
#define MTHREADS 256
#define CSTR 24             // floats per (b,cam) struct

// ---- transpose (bbox-restricted) + (block 0) setup -----------------------
__global__ __launch_bounds__(TTHREADS) void transpose_fm(
    const float* __restrict__ fm, __half* __restrict__ fmH,
    const float* __restrict__ gc, const float* __restrict__ space_c,
    const float* __restrict__ space_s, const float* __restrict__ sub_s,
    const float* __restrict__ centers, const float* __restrict__ trans,
    const float* __restrict__ cam_R, const float* __restrict__ cam_T,
    const float* __restrict__ cam_f, const float* __restrict__ cam_c,
    float* __restrict__ camS, int* __restrict__ bwin,
    float* __restrict__ out, int B)
{
    const int t = threadIdx.x;
    const int cb = blockIdx.y;               // cam*B + b (fm layout order)
    const int cam = cb / B, b = cb - cam * B;
    const int bk = b * NCAM + cam;           // raw param layout [B][NCAM]

    if (blockIdx.x == 0 && blockIdx.y == 0) {
        if (t < B) {                     // per-b window + offset (exact ref math)
            const int bb = t;
            #pragma unroll
            for (int d = 0; d < 3; ++d) {
                float ssz = space_s[d], sc = space_c[d], sub = sub_s[d];
                int   fn  = (int)(ssz / sub * (CUBE - 1.0f)) + 1;
                float fnf = (float)fn;
                float scale = (fnf - 1.0f) / ssz;
                float bias  = -sub / 2.0f / ssz * (fnf - 1.0f) - scale * (sc - ssz / 2.0f);
                int ctl = (int)rintf(gc[bb*7 + d] * scale + bias);
                int mask = 0;
                if (d < 2) {
                    mask = (int)((1.0f - gc[bb*7 + 5 + d]) / 2.0f * (CUBE - 1.0f));
                    if (mask < 0) mask = 0;
                }
                int st = max(ctl + mask, 0);
                int en = min(ctl + CUBE - mask, fn);
                en = max(en, st + 1);
                bwin[bb*12 + d]     = ctl;
                bwin[bb*12 + 3 + d] = st;
                bwin[bb*12 + 6 + d] = en;
                out[(size_t)B * NC * NVOX + bb*3 + d] =
                    (float)ctl / (fnf - 1.0f) * ssz - ssz / 2.0f + sub / 2.0f;
            }
            bwin[t*12 + 9] = (gc[t*7 + 3] >= 0.0f) ? 1 : 0;
        }
        if (t < B * NCAM) {              // per-(b,cam) composed projection
            const int k = t;
            float sA[3], bA[3];
            #pragma unroll
            for (int d = 0; d < 3; ++d) {
                float ssz = space_s[d], sub = sub_s[d];
                int   fn  = (int)(ssz / sub * (CUBE - 1.0f)) + 1;
                sA[d] = ssz / ((float)fn - 1.0f);
                bA[d] = space_c[d] - ssz * 0.5f;
            }
            const float* R = cam_R + k*9;
            const float* T = cam_T + k*3;
            float* P = camS + (size_t)k * CSTR;
            #pragma unroll
            for (int i = 0; i < 3; ++i) {
                #pragma unroll
                for (int d = 0; d < 3; ++d) P[i*3 + d] = R[i*3 + d] * sA[d];
                P[9 + i] = R[i*3+0]*(bA[0]-T[0]) + R[i*3+1]*(bA[1]-T[1]) + R[i*3+2]*(bA[2]-T[2]);
            }
            P[12] = cam_f[k*2+0];  P[13] = cam_f[k*2+1];
            P[14] = cam_c[k*2+0];  P[15] = cam_c[k*2+1];
            P[16] = fmaxf(centers[k*2+0]*2.0f, centers[k*2+1]*2.0f);
            const float* tr = trans + k*6;
            const float KX = 60.0f/239.0f, KY = 32.0f/127.0f; // fold 0.25*(2/HM)*halfdim
            P[17] = tr[0]*KX;  P[18] = tr[1]*KX;  P[19] = tr[2]*KX - 120.0f;
            P[20] = tr[3]*KY;  P[21] = tr[4]*KY;  P[22] = tr[5]*KY - 64.0f;
            P[23] = 0.0f;
        }
    }

    // ---- redundant per-block bbox of the sampled region (uniform math) ----
    float sA[3], bA[3];
    #pragma unroll
    for (int d = 0; d < 3; ++d) {
        float ssz = space_s[d], sub = sub_s[d];
        int fn = (int)(ssz / sub * (CUBE - 1.0f)) + 1;
        sA[d] = ssz / ((float)fn - 1.0f);
        bA[d] = space_c[d] - ssz * 0.5f;
    }
    const float* R = cam_R + bk*9;
    const float* T = cam_T + bk*3;
    float M[9], tv[3];
    #pragma unroll
    for (int i = 0; i < 3; ++i) {
        #pragma unroll
        for (int d = 0; d < 3; ++d) M[i*3+d] = R[i*3+d] * sA[d];
        tv[i] = R[i*3+0]*(bA[0]-T[0]) + R[i*3+1]*(bA[1]-T[1]) + R[i*3+2]*(bA[2]-T[2]);
    }
    const float f0 = cam_f[bk*2+0], f1 = cam_f[bk*2+1];
    const float c0 = cam_c[bk*2+0], c1 = cam_c[bk*2+1];
    const float mw = fmaxf(centers[bk*2+0]*2.0f, centers[bk*2+1]*2.0f);
    const float* tr = trans + bk*6;
    const float KX = 60.0f/239.0f, KY = 32.0f/127.0f;
    const float ax = tr[0]*KX, bx_ = tr[1]*KX, cxo = tr[2]*KX - 120.0f;
    const float ay = tr[3]*KY, by_ = tr[4]*KY, cyo = tr[5]*KY - 64.0f;

    float ctlf[3];
    #pragma unroll
    for (int d = 0; d < 3; ++d) {
        float ssz = space_s[d], sc = space_c[d], sub = sub_s[d];
        int fn = (int)(ssz / sub * (CUBE - 1.0f)) + 1;
        float fnf = (float)fn;
        float scale = (fnf - 1.0f) / ssz;
        float bias = -sub/2.0f/ssz*(fnf-1.0f) - scale*(sc - ssz/2.0f);
        ctlf[d] = rintf(gc[b*7+d]*scale + bias);
    }

    float pxmin = 1e30f, pxmax = -1e30f, pymin = 1e30f, pymax = -1e30f;
    bool ok = true;
    #pragma unroll
    for (int ci = 0; ci < 8; ++ci) {
        float vx = ctlf[0] + ((ci & 1) ? 63.0f : 0.0f);
        float vy = ctlf[1] + ((ci & 2) ? 63.0f : 0.0f);
        float vz = ctlf[2] + ((ci & 4) ? 63.0f : 0.0f);
        float X0 = fmaf(M[0],vx, fmaf(M[1],vy, fmaf(M[2],vz, tv[0])));
        float X1 = fmaf(M[3],vx, fmaf(M[4],vy, fmaf(M[5],vz, tv[1])));
        float X2 = fmaf(M[6],vx, fmaf(M[7],vy, fmaf(M[8],vz, tv[2])));
        ok = ok && (X2 > 1e-3f);
        float rz = __builtin_amdgcn_rcpf(X2);
        float px = fmaf(f0*X0, rz, c0);
        float py = fmaf(f1*X1, rz, c1);
        pxmin = fminf(pxmin, px); pxmax = fmaxf(pxmax, px);
        pymin = fminf(pymin, py); pymax = fmaxf(pymax, py);
    }
    int bbx0, bbx1, bby0, bby1;
    if (ok) {
        float pxl = fminf(fmaxf(pxmin,-1.0f),mw), pxh = fminf(fmaxf(pxmax,-1.0f),mw);
        float pyl = fminf(fmaxf(pymin,-1.0f),mw), pyh = fminf(fmaxf(pymax,-1.0f),mw);
        float ixlo = (ax>0.f?ax*pxl:ax*pxh) + (bx_>0.f?bx_*pyl:bx_*pyh) + cxo;
        float ixhi = (ax>0.f?ax*pxh:ax*pxl) + (bx_>0.f?bx_*pyh:bx_*pyl) + cxo;
        ixlo = fminf(fmaxf(ixlo,-132.0f),132.0f) + 119.5f;
        ixhi = fminf(fmaxf(ixhi,-132.0f),132.0f) + 119.5f;
        float iylo = (ay>0.f?ay*pxl:ay*pxh) + (by_>0.f?by_*pyl:by_*pyh) + cyo;
        float iyhi = (ay>0.f?ay*pxh:ay*pxl) + (by_>0.f?by_*pyh:by_*pyl) + cyo;
        iylo = fminf(fmaxf(iylo,-70.4f),70.4f) + 63.5f;
        iyhi = fminf(fmaxf(iyhi,-70.4f),70.4f) + 63.5f;
        bbx0 = max((int)floorf(ixlo) - 1, 0);
        bbx1 = min((int)floorf(ixhi) + 2, FW-1);
        bby0 = max((int)floorf(iylo) - 1, 0);
        bby1 = min((int)floorf(iyhi) + 2, FH-1);
    } else {
        bbx0 = 0; bbx1 = FW-1; bby0 = 0; bby1 = FH-1;
    }

    // ---- stage only bbox pixels ----
    const int p0  = blockIdx.x * TTHREADS;
    const int rlo = p0 / FW, rhi = (p0 + TTHREADS - 1) / FW;
    if (rhi < bby0 || rlo > bby1) return;
    const int p   = p0 + t;
    const int pyy = p / FW, pxx = p - pyy * FW;
    if (pyy < bby0 || pyy > bby1 || pxx < bbx0 || pxx > bbx1) return;

    const float* src = fm + (size_t)cb * NC * HW + p;
    __half v[NCP];
    #pragma unroll
    for (int c = 0; c < NC; ++c) v[c] = __float2half(src[(size_t)c * HW]);
    v[15] = __float2half(0.0f);
    uint4* dst = (uint4*)(fmH + ((size_t)cb * HW + p) * NCP);
    dst[0] = *(const uint4*)(v);
    dst[1] = *(const uint4*)(v + 8);
}

// fused f16->f32 multiply-add: acc += wt * half(lo/hi of wrd)
#define FMA_MIX2(lo, hi, wt, wrd)                                             \
    asm("v_fma_mix_f32 %0, %1, %2, %0 op_sel_hi:[0,1,0]"                      \
        : "+v"(lo) : "v"(wt), "v"(wrd));                                      \
    asm("v_fma_mix_f32 %0, %1, %2, %0 op_sel:[0,1,0] op_sel_hi:[0,1,0]"       \
        : "+v"(hi) : "v"(wt), "v"(wrd));

// 15 channels: skip the dead pad-channel FMA
#define TAPFMA(wt, A, Bv)                                                     \
    FMA_MIX2(acc[0],  acc[1],  wt, A.x)                                       \
    FMA_MIX2(acc[2],  acc[3],  wt, A.y)                                       \
    FMA_MIX2(acc[4],  acc[5],  wt, A.z)                                       \
    FMA_MIX2(acc[6],  acc[7],  wt, A.w)                                       \
    FMA_MIX2(acc[8],  acc[9],  wt, Bv.x)                                      \
    FMA_MIX2(acc[10], acc[11], wt, Bv.y)                                      \
    FMA_MIX2(acc[12], acc[13], wt, Bv.z)                                      \
    asm("v_fma_mix_f32 %0, %1, %2, %0 op_sel_hi:[0,1,0]"                      \
        : "+v"(acc[14]) : "v"(wt), "v"(Bv.w));

// ---- main: R9 shape (composed constants + XCD-chunked swizzle) -----------
__global__ __launch_bounds__(MTHREADS) void proj_main(
    const __half* __restrict__ fmH,      // [NCAM][B][HW][16] f16
    const float* __restrict__ camS,      // [B*NCAM][CSTR]
    const int* __restrict__ bwin,        // [B][12]: ctl[3], st[3], en[3], flag
    float* __restrict__ out, int B)
{
    const unsigned nwg = gridDim.x;
    const unsigned q = nwg >> 3, r = nwg & 7;
    const unsigned xcd = blockIdx.x & 7, idx = blockIdx.x >> 3;
    const unsigned wgid = (xcd < r ? xcd * (q + 1) : r * (q + 1) + (xcd - r) * q) + idx;

    const int b = wgid >> 10;                    // 1024 blocks per b
    const int n = (int)(wgid & 1023) * MTHREADS + threadIdx.x;
    const int vi = n >> 12, vj = (n >> 6) & 63, vk = n & 63;

    const int* W = bwin + b*12;
    const int fx = W[0] + vi, fy = W[1] + vj, fz = W[2] + vk;
    const bool valid = (fx >= W[3]) & (fx < W[6])
                     & (fy >= W[4]) & (fy < W[7])
                     & (fz >= W[5]) & (fz < W[8])
                     & (W[9] != 0);

    float acc[15];
    #pragma unroll
    for (int c = 0; c < 15; ++c) acc[c] = 0.0f;

    if (valid) {
        const float fxf = (float)fx, fyf = (float)fy, fzf = (float)fz;
        const float* cs = camS + (size_t)(b * NCAM) * CSTR;

        #pragma unroll
        for (int cam = 0; cam < NCAM; ++cam) {
            const float* P = cs + cam * CSTR;
            float X0 = fmaf(P[0], fxf, fmaf(P[1], fyf, fmaf(P[2], fzf, P[9])));
            float X1 = fmaf(P[3], fxf, fmaf(P[4], fyf, fmaf(P[5], fzf, P[10])));
            float X2 = fmaf(P[6], fxf, fmaf(P[7], fyf, fmaf(P[8], fzf, P[11])));
            float rz = __builtin_amdgcn_rcpf(X2);
            float px = fmaf(P[12]*X0, rz, P[14]);
            float py = fmaf(P[13]*X1, rz, P[15]);
            float mw = P[16];
            px = fminf(fmaxf(px, -1.0f), mw);
            py = fminf(fmaxf(py, -1.0f), mw);
            float ixf = fminf(fmaxf(fmaf(P[17], px, fmaf(P[18], py, P[19])), -132.0f), 132.0f) + 119.5f;
            float iyf = fminf(fmaxf(fmaf(P[20], px, fmaf(P[21], py, P[22])), -70.4f), 70.4f) + 63.5f;
            float x0f = floorf(ixf), y0f = floorf(iyf);
            float wx1 = ixf - x0f,  wy1 = iyf - y0f;
            float wx0 = 1.0f - wx1, wy0 = 1.0f - wy1;
            int x0 = (int)x0f, y0 = (int)y0f, x1 = x0 + 1, y1 = y0 + 1;
            bool vx0 = (unsigned)x0 <= (FW-1), vx1 = (unsigned)x1 <= (FW-1);
            bool vy0 = (unsigned)y0 <= (FH-1), vy1 = (unsigned)y1 <= (FH-1);
            float w0 = (vx0 && vy0) ? wx0*wy0 : 0.0f;
            float w1 = (vx1 && vy0) ? wx1*wy0 : 0.0f;
            float w2 = (vx0 && vy1) ? wx0*wy1 : 0.0f;
            float w3 = (vx1 && vy1) ? wx1*wy1 : 0.0f;
            int xc0 = min(max(x0,0),FW-1), xc1 = min(max(x1,0),FW-1);
            int yc0 = min(max(y0,0),FH-1), yc1 = min(max(y1,0),FH-1);

            const __half* bp = fmH + (size_t)(cam*B + b) * HW * NCP;
            const uint4* q0 = (const uint4*)(bp + (size_t)(yc0*FW + xc0) * NCP);
            const uint4* q1 = (const uint4*)(bp + (size_t)(yc0*FW + xc1) * NCP);
            const uint4* q2 = (const uint4*)(bp + (size_t)(yc1*FW + xc0) * NCP);
            const uint4* q3 = (const uint4*)(bp + (size_t)(yc1*FW + xc1) * NCP);
            uint4 a0 = q0[0], b0 = q0[1];
            uint4 a1 = q1[0], b1 = q1[1];
            uint4 a2 = q2[0], b2 = q2[1];
            uint4 a3 = q3[0], b3 = q3[1];

            TAPFMA(w0, a0, b0)
            TAPFMA(w1, a1, b1)
            TAPFMA(w2, a2, b2)
            TAPFMA(w3, a3, b3)
        }
    }

    const float RINV = 0.19999996000000800f;  // 1/(5+1e-6)
    #pragma unroll
    for (int c = 0; c < NC; ++c) {
        float v = fminf(fmaxf(acc[c] * RINV, 0.0f), 1.0f);
        out[((size_t)(b*NC + c)) * NVOX + n] = v;
    }
}

// ---- fallback (round-1 style, f32 direct) if ws is too small ----
__global__ __launch_bounds__(256) void proj_fallback(
    const float* __restrict__ fm, const float* __restrict__ gc,
    const float* __restrict__ space_center, const float* __restrict__ space_size,
    const float* __restrict__ sub_size, const float* __restrict__ centers,
    const float* __restrict__ trans, const float* __restrict__ cam_R,
    const float* __restrict__ cam_T, const float* __restrict__ cam_f,
    const float* __restrict__ cam_c, float* __restrict__ out, int B)
{
    const int b = blockIdx.x / (NVOX/256);
    const int n = (blockIdx.x % (NVOX/256)) * 256 + threadIdx.x;
    float ctlf[3], fnf[3], sc[3], ssz[3];
    int   ctl[3], st[3], en[3];
    #pragma unroll
    for (int d = 0; d < 3; ++d) {
        ssz[d] = space_size[d];
        sc[d]  = space_center[d];
        float sub = sub_size[d];
        int fn = (int)(ssz[d] / sub * (CUBE - 1.0f)) + 1;
        fnf[d] = (float)fn;
        float scale = (fnf[d] - 1.0f) / ssz[d];
        float bias  = -sub / 2.0f / ssz[d] * (fnf[d] - 1.0f)
                      - scale * (sc[d] - ssz[d] / 2.0f);
        int c_tl = (int)rintf(gc[b*7 + d] * scale + bias);
        ctl[d]  = c_tl;  ctlf[d] = (float)c_tl;
        int mask = 0;
        if (d < 2) {
            mask = (int)((1.0f - gc[b*7 + 5 + d]) / 2.0f * (CUBE - 1.0f));
            if (mask < 0) mask = 0;
        }
        st[d] = max(c_tl + mask, 0);
        int e = min(c_tl + CUBE - mask, fn);
        en[d] = max(e, st[d] + 1);
    }
    if (n < 3) {
        int d = n;
        out[(size_t)B * NC * NVOX + b*3 + d] =
            ctlf[d] / (fnf[d] - 1.0f) * ssz[d] - ssz[d] / 2.0f + sub_size[d] / 2.0f;
    }
    const int vi = n >> 12, vj = (n >> 6) & 63, vk = n & 63;
    const int fx = ctl[0] + vi, fy = ctl[1] + vj, fz = ctl[2] + vk;
    const bool valid = (fx >= st[0]) & (fx < en[0]) & (fy >= st[1]) & (fy < en[1])
                     & (fz >= st[2]) & (fz < en[2]) & (gc[b*7 + 3] >= 0.0f);
    float acc[NC];
    #pragma unroll
    for (int c = 0; c < NC; ++c) acc[c] = 0.0f;
    if (valid) {
        const float wxw = sc[0] - ssz[0]*0.5f + (float)fx / (fnf[0]-1.0f) * ssz[0];
        const float wyw = sc[1] - ssz[1]*0.5f + (float)fy / (fnf[1]-1.0f) * ssz[1];
        const float wzw = sc[2] - ssz[2]*0.5f + (float)fz / (fnf[2]-1.0f) * ssz[2];
        for (int cam = 0; cam < NCAM; ++cam) {
            const int bk = b*NCAM + cam;
            const float* R = cam_R + bk*9;
            const float* T = cam_T + bk*3;
            float r0 = wxw - T[0], r1 = wyw - T[1], r2 = wzw - T[2];
            float X0 = R[0]*r0 + R[1]*r1 + R[2]*r2;
            float X1 = R[3]*r0 + R[4]*r1 + R[5]*r2;
            float X2 = R[6]*r0 + R[7]*r1 + R[8]*r2;
            float px = cam_f[bk*2+0]*X0/X2 + cam_c[bk*2+0];
            float py = cam_f[bk*2+1]*X1/X2 + cam_c[bk*2+1];
            float maxwh = fmaxf(centers[bk*2+0]*2.0f, centers[bk*2+1]*2.0f);
            px = fminf(fmaxf(px, -1.0f), maxwh);
            py = fminf(fmaxf(py, -1.0f), maxwh);
            const float* tr = trans + bk*6;
            float tx = (tr[0]*px + tr[1]*py + tr[2]) * 0.25f;
            float ty = (tr[3]*px + tr[4]*py + tr[5]) * 0.25f;
            float gx = fminf(fmaxf(tx/239.0f*2.0f - 1.0f, -1.1f), 1.1f);
            float gy = fminf(fmaxf(ty/127.0f*2.0f - 1.0f, -1.1f), 1.1f);
            float ixf = (gx + 1.0f)*(FW*0.5f) - 0.5f;
            float iyf = (gy + 1.0f)*(FH*0.5f) - 0.5f;
            float x0f = floorf(ixf), y0f = floorf(iyf);
            float wx1 = ixf - x0f,  wy1 = iyf - y0f;
            float wx0 = 1.0f - wx1, wy0 = 1.0f - wy1;
            int x0 = (int)x0f, y0 = (int)y0f, x1 = x0 + 1, y1 = y0 + 1;
            bool vx0 = (x0 >= 0) & (x0 <= FW-1), vx1 = (x1 >= 0) & (x1 <= FW-1);
            bool vy0 = (y0 >= 0) & (y0 <= FH-1), vy1 = (y1 >= 0) & (y1 <= FH-1);
            float w00 = wx0*wy0*(float)(vx0 & vy0);
            float w10 = wx1*wy0*(float)(vx1 & vy0);
            float w01 = wx0*wy1*(float)(vx0 & vy1);
            float w11 = wx1*wy1*(float)(vx1 & vy1);
            int xc0 = min(max(x0,0),FW-1), xc1 = min(max(x1,0),FW-1);
            int yc0 = min(max(y0,0),FH-1), yc1 = min(max(y1,0),FH-1);
            int o00 = yc0*FW + xc0, o10 = yc0*FW + xc1;
            int o01 = yc1*FW + xc0, o11 = yc1*FW + xc1;
            const float* base = fm + ((size_t)(cam*B + b)) * NC * HW;
            #pragma unroll
            for (int c = 0; c < NC; ++c) {
                const float* p = base + c*HW;
                acc[c] += w00*p[o00] + w10*p[o10] + w01*p[o01] + w11*p[o11];
            }
        }
    }
    const float invd = (float)(5.0 + 1e-6);
    #pragma unroll
    for (int c = 0; c < NC; ++c) {
        float v = acc[c] / invd;
        v = fminf(fmaxf(v, 0.0f), 1.0f);
        out[((size_t)(b*NC + c)) * NVOX + n] = v;
    }
}

extern "C" void kernel_launch(void* const* d_in, const int* in_sizes, int n_in,
                              void* d_out, int out_size, void* d_ws, size_t ws_size,
                              hipStream_t stream) {
    const float* fm        = (const float*)d_in[0];
    const float* gc        = (const float*)d_in[1];
    const float* space_c   = (const float*)d_in[2];
    const float* space_s   = (const float*)d_in[3];
    const float* sub_s     = (const float*)d_in[4];
    const float* centers   = (const float*)d_in[6];
    const float* trans     = (const float*)d_in[7];
    const float* cam_R     = (const float*)d_in[8];
    const float* cam_T     = (const float*)d_in[9];
    const float* cam_f     = (const float*)d_in[10];
    const float* cam_c     = (const float*)d_in[11];
    float* out = (float*)d_out;
    const int B = in_sizes[1] / 7;

    const size_t FMHB   = (size_t)NCAM * B * HW * NCP * sizeof(__half);
    const size_t CAMOFF = (FMHB + 255) & ~(size_t)255;
    const size_t BWOFF  = (CAMOFF + (size_t)B * NCAM * CSTR * 4 + 255) & ~(size_t)255;
    const size_t NEED   = BWOFF + (size_t)B * 48;

    if (ws_size >= NEED) {
        __half* fmH  = (__half*)d_ws;
        float*  camS = (float*)((char*)d_ws + CAMOFF);
        int*    bwin = (int*)((char*)d_ws + BWOFF);
        dim3 tg(HW / TTHREADS, NCAM * B);
        hipLaunchKernelGGL(transpose_fm, tg, dim3(TTHREADS), 0, stream,
                           fm, fmH, gc, space_c, space_s, sub_s, centers, trans,
                           cam_R, cam_T, cam_f, cam_c, camS, bwin, out, B);
        dim3 grid(B * 1024), block(MTHREADS);
        hipLaunchKernelGGL(proj_main, grid, block, 0, stream,
                           fmH, camS, bwin, out, B);
    } else {
        dim3 grid(B * (NVOX/256)), block(256);
        hipLaunchKernelGGL(proj_fallback, grid, block, 0, stream,
                           fm, gc, space_c, space_s, sub_s,
                           centers, trans, cam_R, cam_T, cam_f, cam_c, out, B);
    }
}